// Round 11
// baseline (313.891 us; speedup 1.0000x reference)
//
#include <hip/hip_runtime.h>

// row_attention_maxindex on MI355X — R15: flash XCD swizzle + y elimination.
// (1) ra_flash: 512 blocks = 8 (side,b) groups x 64 q-tiles. XCD-group
//     swizzle bx=(h&7)*64+(h>>3) puts each group on one XCD -> its 2MB
//     phi+g set fits the 4MB per-XCD L2 (FETCH was 2x unique = thrash).
// (2) y buffer removed: ra_upstats computes up-proj MFMA for stats only
//     (atomics into zeroed accumulators); ra_finm recomputes y via MFMA
//     and writes out = x + BN(y) directly. -33.6MB y traffic; y no longer
//     bf16-rounded (closer to reference).
// ra_projm unchanged from R14 (zeroes stats in block 0).

typedef unsigned short u16;
typedef unsigned int   u32;
typedef float        floatx4 __attribute__((ext_vector_type(4)));
typedef unsigned int uintx4  __attribute__((ext_vector_type(4)));
typedef unsigned int uintx2  __attribute__((ext_vector_type(2)));
typedef _Float16     half8   __attribute__((ext_vector_type(8)));
typedef __fp16       fp16x2  __attribute__((ext_vector_type(2)));

#define HW 4096
#define CB 256
#define RP 128
#define EPSF 1e-5f

static __device__ __forceinline__ u16 f2bf(float f) {
  u32 u = __float_as_uint(f);
  u32 r = u + 0x7FFFu + ((u >> 16) & 1u);   // RNE
  return (u16)(r >> 16);
}
static __device__ __forceinline__ float bf2f(u16 h) {
  return __uint_as_float(((u32)h) << 16);
}
static __device__ __forceinline__ u16 f2h(float f) {
  _Float16 h = (_Float16)f;                 // RNE
  return __builtin_bit_cast(u16, h);
}
static __device__ __forceinline__ float h2f(u16 h) {
  return (float)__builtin_bit_cast(_Float16, h);
}
static __device__ __forceinline__ half8 as_h8(uintx4 v) {
  return __builtin_bit_cast(half8, v);
}
static __device__ __forceinline__ u32 pkrtz(float a, float b) {
  fp16x2 h = __builtin_amdgcn_cvt_pkrtz(a, b);
  return __builtin_bit_cast(u32, h);
}
static __device__ __forceinline__ u32 pk2h(float a, float b) {  // RNE pair
  return (u32)f2h(a) | ((u32)f2h(b) << 16);
}
// Barrier with DS-visibility only: does NOT drain vmcnt.
static __device__ __forceinline__ void barrier_nodrain() {
  __builtin_amdgcn_sched_barrier(0);
  asm volatile("s_waitcnt lgkmcnt(0)" ::: "memory");
  __builtin_amdgcn_s_barrier();
  __builtin_amdgcn_sched_barrier(0);
}

union Pk4 { u16 u[4]; uintx2 v; };

// ---------------------------------------------------------------------------
// MFMA mega-projection: 6 projections, blockIdx>>7 selects config. (R14)
// ---------------------------------------------------------------------------
struct ProjCfg {
  const float* x; const float* w; const float* bias;
  const float* add; const float* pre; u16* out;
  int wstride; int transposed;
};
struct ProjCfg6 { ProjCfg c[6]; };

#define XSTR 40   // u16 stride of [128][32] fp16 LDS tiles

__global__ __launch_bounds__(256) void ra_projm(ProjCfg6 cfg, float* stz)
{
  __shared__ u16 x_lds[128 * XSTR];   // [pos][c32]
  __shared__ u16 w_lds[128 * XSTR];   // [r][c32]
  if (blockIdx.x == 0) {              // zero stats accumulators (1024 floats)
    ((floatx4*)stz)[threadIdx.x] = (floatx4)0.0f;
  }
  const ProjCfg C = cfg.c[blockIdx.x >> 7];
  const int inner = blockIdx.x & 127;       // b(4) x posb(32)
  const int b    = inner >> 5;
  const int pos0 = (inner & 31) * 128;
  const int tid  = threadIdx.x;
  const int wv   = tid >> 6;
  const int lane = tid & 63;
  const int ln16 = lane & 15;
  const int quad = lane >> 4;
  const int mbase = wv * 32;

  const int xc0 = (tid & 7) * 4, xp0 = (tid >> 3) * 4;   // x: 4c x 4pos
  const int wrr = tid >> 1, wch = (tid & 1) * 16;        // w: 1r x 16c
  const bool walign = (C.wstride & 3) == 0;

  floatx4 acc[2][8];
  #pragma unroll
  for (int mt = 0; mt < 2; mt++)
    #pragma unroll
    for (int nt = 0; nt < 8; nt++) acc[mt][nt] = (floatx4)0.0f;

  floatx4 xr[4];
  floatx4 ww4[4];
  {
    #pragma unroll
    for (int i = 0; i < 4; i++)
      xr[i] = *(const floatx4*)(C.x + (size_t)(b * CB + xc0 + i) * HW + pos0 + xp0);
    const float* wp = C.w + (size_t)wrr * C.wstride + wch;
    if (walign) {
      #pragma unroll
      for (int i = 0; i < 4; i++) ww4[i] = *(const floatx4*)(wp + i * 4);
    } else {
      #pragma unroll
      for (int i = 0; i < 4; i++)
        #pragma unroll
        for (int jj = 0; jj < 4; jj++) ww4[i][jj] = wp[i * 4 + jj];
    }
  }

  #pragma unroll 1
  for (int cc = 0; cc < 8; ++cc) {
    barrier_nodrain();   // prev chunk's LDS reads complete -> safe overwrite
    #pragma unroll
    for (int pp = 0; pp < 4; pp++) {
      uintx2 v;
      v[0] = pk2h(xr[0][pp], xr[1][pp]);
      v[1] = pk2h(xr[2][pp], xr[3][pp]);
      *(uintx2*)&x_lds[(xp0 + pp) * XSTR + xc0] = v;
    }
    {
      uintx4 v0, v1;
      v0[0] = pk2h(ww4[0][0], ww4[0][1]); v0[1] = pk2h(ww4[0][2], ww4[0][3]);
      v0[2] = pk2h(ww4[1][0], ww4[1][1]); v0[3] = pk2h(ww4[1][2], ww4[1][3]);
      v1[0] = pk2h(ww4[2][0], ww4[2][1]); v1[1] = pk2h(ww4[2][2], ww4[2][3]);
      v1[2] = pk2h(ww4[3][0], ww4[3][1]); v1[3] = pk2h(ww4[3][2], ww4[3][3]);
      *(uintx4*)&w_lds[wrr * XSTR + wch]     = v0;
      *(uintx4*)&w_lds[wrr * XSTR + wch + 8] = v1;
    }
    if (cc < 7) {   // prefetch next chunk; stays in flight across MFMA
      const int c2 = (cc + 1) * 32;
      #pragma unroll
      for (int i = 0; i < 4; i++)
        xr[i] = *(const floatx4*)(C.x + (size_t)(b * CB + c2 + xc0 + i) * HW + pos0 + xp0);
      const float* wp = C.w + (size_t)wrr * C.wstride + c2 + wch;
      if (walign) {
        #pragma unroll
        for (int i = 0; i < 4; i++) ww4[i] = *(const floatx4*)(wp + i * 4);
      } else {
        #pragma unroll
        for (int i = 0; i < 4; i++)
          #pragma unroll
          for (int jj = 0; jj < 4; jj++) ww4[i][jj] = wp[i * 4 + jj];
      }
    }
    barrier_nodrain();   // tile visible (lgkm only, vmcnt alive)
    if (!C.transposed) {
      half8 a0 = as_h8(*(const uintx4*)&w_lds[(mbase + ln16) * XSTR + quad * 8]);
      half8 a1 = as_h8(*(const uintx4*)&w_lds[(mbase + 16 + ln16) * XSTR + quad * 8]);
      #pragma unroll
      for (int nt = 0; nt < 8; nt++) {
        half8 bf = as_h8(*(const uintx4*)&x_lds[(nt * 16 + ln16) * XSTR + quad * 8]);
        acc[0][nt] = __builtin_amdgcn_mfma_f32_16x16x32_f16(a0, bf, acc[0][nt], 0, 0, 0);
        acc[1][nt] = __builtin_amdgcn_mfma_f32_16x16x32_f16(a1, bf, acc[1][nt], 0, 0, 0);
      }
    } else {
      half8 a0 = as_h8(*(const uintx4*)&x_lds[(mbase + ln16) * XSTR + quad * 8]);
      half8 a1 = as_h8(*(const uintx4*)&x_lds[(mbase + 16 + ln16) * XSTR + quad * 8]);
      #pragma unroll
      for (int nt = 0; nt < 8; nt++) {
        half8 bf = as_h8(*(const uintx4*)&w_lds[(nt * 16 + ln16) * XSTR + quad * 8]);
        acc[0][nt] = __builtin_amdgcn_mfma_f32_16x16x32_f16(a0, bf, acc[0][nt], 0, 0, 0);
        acc[1][nt] = __builtin_amdgcn_mfma_f32_16x16x32_f16(a1, bf, acc[1][nt], 0, 0, 0);
      }
    }
  }

  if (!C.transposed) {
    #pragma unroll
    for (int mt = 0; mt < 2; mt++) {
      const int r0 = mbase + mt * 16 + quad * 4;
      floatx4 bi = *(const floatx4*)(C.bias + r0);
      float wc[4];
      if (C.pre) {
        #pragma unroll
        for (int rr = 0; rr < 4; rr++) wc[rr] = C.w[(size_t)(r0 + rr) * C.wstride + 256];
      }
      #pragma unroll
      for (int nt = 0; nt < 8; nt++) {
        const int pos = pos0 + nt * 16 + ln16;
        floatx4 v = acc[mt][nt];
        #pragma unroll
        for (int rr = 0; rr < 4; rr++) v[rr] += bi[rr];
        if (C.pre) {
          const float pv = C.pre[(size_t)b * HW + pos] * (1.f / 128.f);
          #pragma unroll
          for (int rr = 0; rr < 4; rr++) v[rr] += pv * wc[rr];
        }
        if (C.add) {
          #pragma unroll
          for (int rr = 0; rr < 4; rr++)
            v[rr] += C.add[(size_t)(b * RP + r0 + rr) * HW + pos];
        }
        Pk4 pk;
        #pragma unroll
        for (int rr = 0; rr < 4; rr++) pk.u[rr] = f2h(v[rr]);
        *(uintx2*)(C.out + (size_t)(b * HW + pos) * RP + r0) = pk.v;
      }
    }
  } else {
    #pragma unroll
    for (int nt = 0; nt < 8; nt++) {
      const int r = nt * 16 + ln16;
      const float bs = C.bias[r];
      #pragma unroll
      for (int mt = 0; mt < 2; mt++) {
        const int pv = pos0 + mbase + mt * 16 + quad * 4;
        floatx4 v = acc[mt][nt];
        Pk4 pk;
        #pragma unroll
        for (int rr = 0; rr < 4; rr++) pk.u[rr] = f2h(v[rr] + bs);
        *(uintx2*)(C.out + (size_t)(b * RP + r) * HW + pv) = pk.v;
      }
    }
  }
}

// ---------------------------------------------------------------------------
// Flash attention, NO split-K (R11) + R15 XCD-group swizzle: the 512 blocks
// are 8 (side,b) groups x 64 q-tiles; hw id h -> logical (h&7)*64+(h>>3)
// puts each group on one XCD so its 2MB phi+g set fits the 4MB L2.
// ---------------------------------------------------------------------------
__global__ __launch_bounds__(256) void ra_flash(
    const u16* __restrict__ thetaL, const u16* __restrict__ phiTL,
    const u16* __restrict__ gTL,
    const u16* __restrict__ thetaR, const u16* __restrict__ phiTR,
    const u16* __restrict__ gTR,
    u16* __restrict__ afterL, u16* __restrict__ afterR,
    float* __restrict__ idxL, float* __restrict__ idxR)
{
  __shared__ uintx4 phi_lds[16 * 65];   // [rchunk8 cb(16)][k(64)]
  __shared__ uintx4 g_lds[8 * 129];     // [kchunk8 kcb(8)][v(128)]
  __shared__ u16 P_lds[4][16 * 76];     // per-wave [q(16)][k(64)], stride 76

  const int tid  = threadIdx.x;
  const int h    = blockIdx.x;
  const int bx   = ((h & 7) << 6) | (h >> 3);   // XCD-group swizzle (512 = 8x64)
  const int side = bx >> 8;
  const int sbx  = bx & 255;
  const u16* __restrict__ theta = side ? thetaR : thetaL;
  const u16* __restrict__ phiT  = side ? phiTR  : phiTL;
  const u16* __restrict__ gT    = side ? gTR    : gTL;

  const int b    = sbx >> 6;
  const int q0   = (sbx & 63) * 64;
  const int wv   = tid >> 6;
  const int lane = tid & 63;
  const int ln16 = lane & 15;
  const int quad = lane >> 4;

  uintx4 aq[4];
  {
    const uintx4* tr = (const uintx4*)(theta + (size_t)(b * HW + q0 + wv * 16 + ln16) * RP);
    #pragma unroll
    for (int c = 0; c < 4; c++) aq[c] = tr[c * 4 + quad];
  }

  // colones A-fragment: row0 = k-in-tile (0..63), row1 = 1, rows 2..15 = 0.
  half8 cf0, cf1;
  {
    #pragma unroll
    for (int i = 0; i < 8; i++) {
      float c0 = (ln16 == 0) ? (float)(quad * 8 + i)      : (ln16 == 1 ? 1.f : 0.f);
      float c1 = (ln16 == 0) ? (float)(32 + quad * 8 + i) : (ln16 == 1 ? 1.f : 0.f);
      cf0[i] = (_Float16)c0;
      cf1[i] = (_Float16)c1;
    }
  }

  floatx4 accO[8];
  #pragma unroll
  for (int v = 0; v < 8; v++) accO[v] = (floatx4)0.0f;
  floatx4 accE  = (floatx4)0.0f;   // even-j: [0]=Σp·kk, [1]=Σp (quad0 rows)
  floatx4 accEo = (floatx4)0.0f;   // odd-j
  float m_q = -3.0e38f;

  const int sk  = tid >> 4, scb = tid & 15;  // phi staging
  const int gv_ = tid >> 3, gcb = tid & 7;   // g staging

  uintx4 sp[4], sg[4];
  #pragma unroll
  for (int i = 0; i < 4; i++) {
    sp[i] = *(const uintx4*)(phiT + (size_t)(b * HW + i * 16 + sk) * RP + scb * 8);
    sg[i] = *(const uintx4*)(gT + (size_t)(b * RP + i * 32 + gv_) * HW + gcb * 8);
  }

  #pragma unroll 1
  for (int j = 0; j < 64; j++) {
    #pragma unroll
    for (int i = 0; i < 4; i++) {
      phi_lds[scb * 65 + i * 16 + sk] = sp[i];
      g_lds[gcb * 129 + i * 32 + gv_] = sg[i];
    }
    if (j < 63) {
      const int k0n = (j + 1) * 64;
      #pragma unroll
      for (int i = 0; i < 4; i++) {
        sp[i] = *(const uintx4*)(phiT + (size_t)(b * HW + k0n + i * 16 + sk) * RP + scb * 8);
        sg[i] = *(const uintx4*)(gT + (size_t)(b * RP + i * 32 + gv_) * HW + k0n + gcb * 8);
      }
    }
    barrier_nodrain();

    floatx4 sf[4];
    #pragma unroll
    for (int s = 0; s < 4; s++) sf[s] = (floatx4)0.0f;
    __builtin_amdgcn_s_setprio(1);
    #pragma unroll
    for (int c = 0; c < 4; c++) {
      half8 bth = as_h8(aq[c]);
      #pragma unroll
      for (int s = 0; s < 4; s++) {
        uintx4 ap = phi_lds[(c * 4 + quad) * 65 + s * 16 + ln16];
        sf[s] = __builtin_amdgcn_mfma_f32_16x16x32_f16(as_h8(ap), bth, sf[s], 0, 0, 0);
      }
    }
    __builtin_amdgcn_s_setprio(0);

    float ms0 = fmaxf(fmaxf(sf[0][0], sf[0][1]), fmaxf(sf[0][2], sf[0][3]));
    float ms1 = fmaxf(fmaxf(sf[1][0], sf[1][1]), fmaxf(sf[1][2], sf[1][3]));
    float ms2 = fmaxf(fmaxf(sf[2][0], sf[2][1]), fmaxf(sf[2][2], sf[2][3]));
    float ms3 = fmaxf(fmaxf(sf[3][0], sf[3][1]), fmaxf(sf[3][2], sf[3][3]));
    float mx = fmaxf(fmaxf(ms0, ms1), fmaxf(ms2, ms3));
    mx = fmaxf(mx, __shfl_xor(mx, 16));
    mx = fmaxf(mx, __shfl_xor(mx, 32));
    if (__any(mx > m_q + 8.f)) {       // wave-uniform, rare in steady state
      const float mnew  = fmaxf(m_q, mx);
      const float alpha = __expf(m_q - mnew);
      m_q = mnew;
      accE *= alpha; accEo *= alpha;
      #pragma unroll
      for (int v = 0; v < 8; v++) accO[v] *= alpha;
    }
    #pragma unroll
    for (int s = 0; s < 4; s++) {
      float p0 = __expf(sf[s][0] - m_q);
      float p1 = __expf(sf[s][1] - m_q);
      float p2 = __expf(sf[s][2] - m_q);
      float p3 = __expf(sf[s][3] - m_q);
      uintx2 pkv;
      pkv[0] = pkrtz(p0, p1);
      pkv[1] = pkrtz(p2, p3);
      *(uintx2*)&P_lds[wv][ln16 * 76 + s * 16 + quad * 4] = pkv;
    }

    // no barrier: P_lds is wave-private; DS ops in-order per wave.
    half8 pb0 = as_h8(*(const uintx4*)&P_lds[wv][ln16 * 76 + quad * 8]);
    half8 pb1 = as_h8(*(const uintx4*)&P_lds[wv][ln16 * 76 + 32 + quad * 8]);
    __builtin_amdgcn_s_setprio(1);
    #pragma unroll
    for (int vt = 0; vt < 8; vt++) {
      uintx4 ag0 = g_lds[quad * 129 + vt * 16 + ln16];
      uintx4 ag1 = g_lds[(4 + quad) * 129 + vt * 16 + ln16];
      accO[vt] = __builtin_amdgcn_mfma_f32_16x16x32_f16(as_h8(ag0), pb0, accO[vt], 0, 0, 0);
      accO[vt] = __builtin_amdgcn_mfma_f32_16x16x32_f16(as_h8(ag1), pb1, accO[vt], 0, 0, 0);
    }
    if (j & 1) {
      accEo = __builtin_amdgcn_mfma_f32_16x16x32_f16(cf0, pb0, accEo, 0, 0, 0);
      accEo = __builtin_amdgcn_mfma_f32_16x16x32_f16(cf1, pb1, accEo, 0, 0, 0);
    } else {
      accE  = __builtin_amdgcn_mfma_f32_16x16x32_f16(cf0, pb0, accE, 0, 0, 0);
      accE  = __builtin_amdgcn_mfma_f32_16x16x32_f16(cf1, pb1, accE, 0, 0, 0);
    }
    __builtin_amdgcn_s_setprio(0);
    barrier_nodrain();
  }

  // epilogue: l = Σp (all j), aC = Σp·kk + 64·Σp(odd j); broadcast via shfl.
  const float l0 = accE[1] + accEo[1];
  const float a0 = accE[0] + accEo[0] + 64.f * accEo[1];
  const float l_all  = __shfl(l0, ln16);
  const float aC_all = __shfl(a0, ln16);

  const int q = q0 + wv * 16 + ln16;
  const size_t p = (size_t)b * HW + q;
  u16* after = side ? afterR : afterL;
  u16* orow = after + p * RP;
  const float invl = 1.f / l_all;
  #pragma unroll
  for (int vt = 0; vt < 8; vt++) {
    uintx2 pkv;
    pkv[0] = pkrtz(accO[vt][0] * invl, accO[vt][1] * invl);
    pkv[1] = pkrtz(accO[vt][2] * invl, accO[vt][3] * invl);
    *(uintx2*)(orow + vt * 16 + quad * 4) = pkv;
  }
  if (quad == 0) {
    float* idx = side ? idxR : idxL;
    idx[p] = (float)(q & 127) - aC_all * invl;
  }
}

// ---------------------------------------------------------------------------
// Up-projection stats only: y = after·up_w + up_b via MFMA, per-channel
// Σy/Σy² partial-reduced and atomicAdd'ed. y is NOT written (ra_finm
// recomputes it). stats accumulators zeroed by ra_projm block 0.
// ---------------------------------------------------------------------------
#define WSTR 136   // u16 stride (272B, 16B-aligned rows)

__global__ __launch_bounds__(256) void ra_upstats(
    const u16* __restrict__ afterL, const u16* __restrict__ afterR,
    const float* __restrict__ w, const float* __restrict__ bias,
    float* __restrict__ stL, float* __restrict__ stR)
{
  __shared__ u16 w_lds[128 * WSTR];   // [co][r]; reused as float scratch
  const int tid  = threadIdx.x;
  const int bx   = blockIdx.x;
  const int side = bx >> 8;
  const int sbx  = bx & 255;
  const u16* __restrict__ after = side ? afterR : afterL;
  const int b    = sbx >> 6;
  const int pos0 = ((sbx >> 1) & 31) * 128;
  const int hc   = sbx & 1;
  const int wv   = tid >> 6;
  const int lane = tid & 63;
  const int ln16 = lane & 15;
  const int quad = lane >> 4;

  {
    const int co = tid >> 1, rh = (tid & 1) * 64;
    const float* wp = w + (size_t)(hc * 128 + co) * RP + rh;
    #pragma unroll
    for (int i = 0; i < 8; i++) {
      floatx4 f0 = *(const floatx4*)(wp + i * 8);
      floatx4 f1 = *(const floatx4*)(wp + i * 8 + 4);
      uintx4 v;
      v[0] = pk2h(f0[0], f0[1]); v[1] = pk2h(f0[2], f0[3]);
      v[2] = pk2h(f1[0], f1[1]); v[3] = pk2h(f1[2], f1[3]);
      *(uintx4*)&w_lds[co * WSTR + rh + i * 8] = v;
    }
  }
  __syncthreads();

  floatx4 acc[2][8];
  #pragma unroll
  for (int mt = 0; mt < 2; mt++)
    #pragma unroll
    for (int nt = 0; nt < 8; nt++) acc[mt][nt] = (floatx4)0.0f;

  #pragma unroll
  for (int kk = 0; kk < 4; kk++) {
    half8 a[2];
    #pragma unroll
    for (int mt = 0; mt < 2; mt++)
      a[mt] = as_h8(*(const uintx4*)(after +
          (size_t)(b * HW + pos0 + wv * 32 + mt * 16 + ln16) * RP + kk * 32 + quad * 8));
    #pragma unroll
    for (int nt = 0; nt < 8; nt++) {
      half8 bf = as_h8(*(const uintx4*)&w_lds[(nt * 16 + ln16) * WSTR + kk * 32 + quad * 8]);
      acc[0][nt] = __builtin_amdgcn_mfma_f32_16x16x32_f16(a[0], bf, acc[0][nt], 0, 0, 0);
      acc[1][nt] = __builtin_amdgcn_mfma_f32_16x16x32_f16(a[1], bf, acc[1][nt], 0, 0, 0);
    }
  }

  // per-channel partials (this block: 128 pos of one b)
  float s_nt[8], q_nt[8];
  #pragma unroll
  for (int nt = 0; nt < 8; nt++) {
    const float bs = bias[hc * 128 + nt * 16 + ln16];
    float s = 0.f, sq = 0.f;
    #pragma unroll
    for (int mt = 0; mt < 2; mt++) {
      #pragma unroll
      for (int rr = 0; rr < 4; rr++) {
        const float yv = acc[mt][nt][rr] + bs;
        s += yv; sq += yv * yv;
      }
    }
    s  += __shfl_xor(s, 16);  s  += __shfl_xor(s, 32);
    sq += __shfl_xor(sq, 16); sq += __shfl_xor(sq, 32);
    s_nt[nt] = s; q_nt[nt] = sq;
  }
  __syncthreads();              // all waves done reading w_lds
  float* scr = (float*)w_lds;   // [0..511]=s per (wv,co), [512..1023]=sq
  if (quad == 0) {
    #pragma unroll
    for (int nt = 0; nt < 8; nt++) {
      scr[wv * 128 + nt * 16 + ln16]       = s_nt[nt];
      scr[512 + wv * 128 + nt * 16 + ln16] = q_nt[nt];
    }
  }
  __syncthreads();
  if (tid < 128) {
    const float s  = scr[tid] + scr[128 + tid] + scr[256 + tid] + scr[384 + tid];
    const float sq = scr[512 + tid] + scr[640 + tid] + scr[768 + tid] + scr[896 + tid];
    float* stats = side ? stR : stL;
    atomicAdd(&stats[2 * (hc * 128 + tid)], s);
    atomicAdd(&stats[2 * (hc * 128 + tid) + 1], sq);
  }
}

// ---------------------------------------------------------------------------
// Fused up-projection + batch-norm + residual: recompute y via MFMA, read
// stats (raw Σy/Σy²) -> mean/rstd, out = x + gamma*(y-mean)*rstd + beta.
// y never touches memory; out written as float4.
// ---------------------------------------------------------------------------
__global__ __launch_bounds__(256) void ra_finm(
    const u16* __restrict__ afterL, const u16* __restrict__ afterR,
    const float* __restrict__ w, const float* __restrict__ bias,
    const float* __restrict__ left, const float* __restrict__ right,
    const float* __restrict__ stL, const float* __restrict__ stR,
    const float* __restrict__ gamma, const float* __restrict__ beta,
    float* __restrict__ out)
{
  __shared__ u16 w_lds[128 * WSTR];   // [co][r]
  const int tid  = threadIdx.x;
  const int bx   = blockIdx.x;
  const int side = bx >> 8;
  const int sbx  = bx & 255;
  const u16* __restrict__ after = side ? afterR : afterL;
  const int b    = sbx >> 6;
  const int pos0 = ((sbx >> 1) & 31) * 128;
  const int hc   = sbx & 1;
  const int wv   = tid >> 6;
  const int lane = tid & 63;
  const int ln16 = lane & 15;
  const int quad = lane >> 4;

  {
    const int co = tid >> 1, rh = (tid & 1) * 64;
    const float* wp = w + (size_t)(hc * 128 + co) * RP + rh;
    #pragma unroll
    for (int i = 0; i < 8; i++) {
      floatx4 f0 = *(const floatx4*)(wp + i * 8);
      floatx4 f1 = *(const floatx4*)(wp + i * 8 + 4);
      uintx4 v;
      v[0] = pk2h(f0[0], f0[1]); v[1] = pk2h(f0[2], f0[3]);
      v[2] = pk2h(f1[0], f1[1]); v[3] = pk2h(f1[2], f1[3]);
      *(uintx4*)&w_lds[co * WSTR + rh + i * 8] = v;
    }
  }
  __syncthreads();

  floatx4 acc[2][8];
  #pragma unroll
  for (int mt = 0; mt < 2; mt++)
    #pragma unroll
    for (int nt = 0; nt < 8; nt++) acc[mt][nt] = (floatx4)0.0f;

  #pragma unroll
  for (int kk = 0; kk < 4; kk++) {
    half8 a[2];
    #pragma unroll
    for (int mt = 0; mt < 2; mt++)
      a[mt] = as_h8(*(const uintx4*)(after +
          (size_t)(b * HW + pos0 + wv * 32 + mt * 16 + ln16) * RP + kk * 32 + quad * 8));
    #pragma unroll
    for (int nt = 0; nt < 8; nt++) {
      half8 bf = as_h8(*(const uintx4*)&w_lds[(nt * 16 + ln16) * WSTR + kk * 32 + quad * 8]);
      acc[0][nt] = __builtin_amdgcn_mfma_f32_16x16x32_f16(a[0], bf, acc[0][nt], 0, 0, 0);
      acc[1][nt] = __builtin_amdgcn_mfma_f32_16x16x32_f16(a[1], bf, acc[1][nt], 0, 0, 0);
    }
  }

  const float* x = side ? right : left;
  const float* stats = side ? stR : stL;
  float* outs = out + (size_t)side * 4194304;
  #pragma unroll
  for (int nt = 0; nt < 8; nt++) {
    const int co = hc * 128 + nt * 16 + ln16;
    const float s = stats[2 * co], sq = stats[2 * co + 1];
    const float mean = s * (1.f / 16384.f);
    const float var  = sq * (1.f / 16384.f) - mean * mean;
    const float rstd = rsqrtf(var + EPSF);
    const float ga = gamma[co], be = beta[co];
    const float bs = bias[co];
    #pragma unroll
    for (int mt = 0; mt < 2; mt++) {
      const int pv = pos0 + wv * 32 + mt * 16 + quad * 4;
      floatx4 xv = *(const floatx4*)(x + (size_t)(b * CB + co) * HW + pv);
      floatx4 o;
      #pragma unroll
      for (int rr = 0; rr < 4; rr++) {
        const float yv = acc[mt][nt][rr] + bs;
        o[rr] = xv[rr] + ga * ((yv - mean) * rstd) + be;
      }
      *(floatx4*)(outs + (size_t)(b * CB + co) * HW + pv) = o;
    }
  }
}

// ---------------------------------------------------------------------------
extern "C" void kernel_launch(void* const* d_in, const int* in_sizes, int n_in,
                              void* d_out, int out_size, void* d_ws, size_t ws_size,
                              hipStream_t stream)
{
  const float* left    = (const float*)d_in[0];
  const float* right   = (const float*)d_in[1];
  const float* pre_l   = (const float*)d_in[2];
  const float* pre_r   = (const float*)d_in[3];
  const float* query_l = (const float*)d_in[4];
  const float* key_l   = (const float*)d_in[5];
  const float* query_r = (const float*)d_in[6];
  const float* key_r   = (const float*)d_in[7];
  const float* theta_w = (const float*)d_in[8];
  const float* theta_b = (const float*)d_in[9];
  const float* phi_w   = (const float*)d_in[10];
  const float* phi_b   = (const float*)d_in[11];
  const float* g_w     = (const float*)d_in[12];
  const float* g_b     = (const float*)d_in[13];
  const float* up_w    = (const float*)d_in[14];
  const float* up_b    = (const float*)d_in[15];
  const float* bn_g    = (const float*)d_in[16];
  const float* bn_b    = (const float*)d_in[17];
  float* out = (float*)d_out;

  char* ws = (char*)d_ws;
  const size_t SZ = (size_t)4 * HW * RP * 2;  // 4 MiB (fp16 [4][4096][128])
  u16* thetaL = (u16*)(ws);
  u16* phiTL  = (u16*)(ws + 1 * SZ);
  u16* gTL    = (u16*)(ws + 2 * SZ);
  u16* thetaR = (u16*)(ws + 3 * SZ);
  u16* phiTR  = (u16*)(ws + 4 * SZ);
  u16* gTR    = (u16*)(ws + 5 * SZ);
  u16* afterL = (u16*)(ws + 6 * SZ);
  u16* afterR = (u16*)(ws + 7 * SZ);
  float* stL  = (float*)(ws + 8 * SZ);
  float* stR  = (float*)(ws + 8 * SZ + 2048);

  dim3 blk(256);
  // side L: x_q=left, x_kv=right, query_l, key_r; side R mirrored.
  ProjCfg6 pc;
  pc.c[0] = { left,  theta_w, theta_b, query_l, pre_l,   thetaL, 257, 0 };
  pc.c[1] = { right, phi_w,   phi_b,   key_r,   nullptr, phiTL,  256, 0 };
  pc.c[2] = { right, g_w,     g_b,     nullptr, nullptr, gTL,    256, 1 };
  pc.c[3] = { right, theta_w, theta_b, query_r, pre_r,   thetaR, 257, 0 };
  pc.c[4] = { left,  phi_w,   phi_b,   key_l,   nullptr, phiTR,  256, 0 };
  pc.c[5] = { left,  g_w,     g_b,     nullptr, nullptr, gTR,    256, 1 };
  ra_projm<<<768, blk, 0, stream>>>(pc, stL);

  ra_flash<<<512, blk, 0, stream>>>(thetaL, phiTL, gTL, thetaR, phiTR, gTR,
                                    afterL, afterR,
                                    out + 8388608, out + 8404992);
  ra_upstats<<<512, blk, 0, stream>>>(afterL, afterR, up_w, up_b, stL, stR);
  ra_finm<<<512, blk, 0, stream>>>(afterL, afterR, up_w, up_b, left, right,
                                   stL, stR, bn_g, bn_b, out);

  (void)in_sizes; (void)n_in; (void)out_size; (void)ws_size;
}

// Round 13
// 309.640 us; speedup vs baseline: 1.0137x; 1.0137x over previous
//
#include <hip/hip_runtime.h>

// row_attention_maxindex on MI355X — R17: revert R16's permlane P-routing
// (failed on HW despite doc-consistent derivation; P back through LDS as in
// R15, which passed). Delta vs R15: XCD-group swizzle added to ra_upstats
// and ra_finm (512 blocks = 8 (side,b) groups x 64; pin each group's
// after[b]+w+x working set to one XCD L2, same bijective remap as flash).

typedef unsigned short u16;
typedef unsigned int   u32;
typedef float        floatx4 __attribute__((ext_vector_type(4)));
typedef unsigned int uintx4  __attribute__((ext_vector_type(4)));
typedef unsigned int uintx2  __attribute__((ext_vector_type(2)));
typedef _Float16     half8   __attribute__((ext_vector_type(8)));
typedef __fp16       fp16x2  __attribute__((ext_vector_type(2)));

#define HW 4096
#define CB 256
#define RP 128
#define EPSF 1e-5f

static __device__ __forceinline__ u16 f2bf(float f) {
  u32 u = __float_as_uint(f);
  u32 r = u + 0x7FFFu + ((u >> 16) & 1u);   // RNE
  return (u16)(r >> 16);
}
static __device__ __forceinline__ float bf2f(u16 h) {
  return __uint_as_float(((u32)h) << 16);
}
static __device__ __forceinline__ u16 f2h(float f) {
  _Float16 h = (_Float16)f;                 // RNE
  return __builtin_bit_cast(u16, h);
}
static __device__ __forceinline__ float h2f(u16 h) {
  return (float)__builtin_bit_cast(_Float16, h);
}
static __device__ __forceinline__ half8 as_h8(uintx4 v) {
  return __builtin_bit_cast(half8, v);
}
static __device__ __forceinline__ u32 pkrtz(float a, float b) {
  fp16x2 h = __builtin_amdgcn_cvt_pkrtz(a, b);
  return __builtin_bit_cast(u32, h);
}
static __device__ __forceinline__ u32 pk2h(float a, float b) {  // RNE pair
  return (u32)f2h(a) | ((u32)f2h(b) << 16);
}
// Barrier with DS-visibility only: does NOT drain vmcnt.
static __device__ __forceinline__ void barrier_nodrain() {
  __builtin_amdgcn_sched_barrier(0);
  asm volatile("s_waitcnt lgkmcnt(0)" ::: "memory");
  __builtin_amdgcn_s_barrier();
  __builtin_amdgcn_sched_barrier(0);
}

union Pk4 { u16 u[4]; uintx2 v; };

// ---------------------------------------------------------------------------
// MFMA mega-projection: 6 projections, blockIdx>>7 selects config. (R14)
// ---------------------------------------------------------------------------
struct ProjCfg {
  const float* x; const float* w; const float* bias;
  const float* add; const float* pre; u16* out;
  int wstride; int transposed;
};
struct ProjCfg6 { ProjCfg c[6]; };

#define XSTR 40   // u16 stride of [128][32] fp16 LDS tiles

__global__ __launch_bounds__(256) void ra_projm(ProjCfg6 cfg, float* stz)
{
  __shared__ u16 x_lds[128 * XSTR];   // [pos][c32]
  __shared__ u16 w_lds[128 * XSTR];   // [r][c32]
  if (blockIdx.x == 0) {              // zero stats accumulators (1024 floats)
    ((floatx4*)stz)[threadIdx.x] = (floatx4)0.0f;
  }
  const ProjCfg C = cfg.c[blockIdx.x >> 7];
  const int inner = blockIdx.x & 127;       // b(4) x posb(32)
  const int b    = inner >> 5;
  const int pos0 = (inner & 31) * 128;
  const int tid  = threadIdx.x;
  const int wv   = tid >> 6;
  const int lane = tid & 63;
  const int ln16 = lane & 15;
  const int quad = lane >> 4;
  const int mbase = wv * 32;

  const int xc0 = (tid & 7) * 4, xp0 = (tid >> 3) * 4;   // x: 4c x 4pos
  const int wrr = tid >> 1, wch = (tid & 1) * 16;        // w: 1r x 16c
  const bool walign = (C.wstride & 3) == 0;

  floatx4 acc[2][8];
  #pragma unroll
  for (int mt = 0; mt < 2; mt++)
    #pragma unroll
    for (int nt = 0; nt < 8; nt++) acc[mt][nt] = (floatx4)0.0f;

  floatx4 xr[4];
  floatx4 ww4[4];
  {
    #pragma unroll
    for (int i = 0; i < 4; i++)
      xr[i] = *(const floatx4*)(C.x + (size_t)(b * CB + xc0 + i) * HW + pos0 + xp0);
    const float* wp = C.w + (size_t)wrr * C.wstride + wch;
    if (walign) {
      #pragma unroll
      for (int i = 0; i < 4; i++) ww4[i] = *(const floatx4*)(wp + i * 4);
    } else {
      #pragma unroll
      for (int i = 0; i < 4; i++)
        #pragma unroll
        for (int jj = 0; jj < 4; jj++) ww4[i][jj] = wp[i * 4 + jj];
    }
  }

  #pragma unroll 1
  for (int cc = 0; cc < 8; ++cc) {
    barrier_nodrain();   // prev chunk's LDS reads complete -> safe overwrite
    #pragma unroll
    for (int pp = 0; pp < 4; pp++) {
      uintx2 v;
      v[0] = pk2h(xr[0][pp], xr[1][pp]);
      v[1] = pk2h(xr[2][pp], xr[3][pp]);
      *(uintx2*)&x_lds[(xp0 + pp) * XSTR + xc0] = v;
    }
    {
      uintx4 v0, v1;
      v0[0] = pk2h(ww4[0][0], ww4[0][1]); v0[1] = pk2h(ww4[0][2], ww4[0][3]);
      v0[2] = pk2h(ww4[1][0], ww4[1][1]); v0[3] = pk2h(ww4[1][2], ww4[1][3]);
      v1[0] = pk2h(ww4[2][0], ww4[2][1]); v1[1] = pk2h(ww4[2][2], ww4[2][3]);
      v1[2] = pk2h(ww4[3][0], ww4[3][1]); v1[3] = pk2h(ww4[3][2], ww4[3][3]);
      *(uintx4*)&w_lds[wrr * XSTR + wch]     = v0;
      *(uintx4*)&w_lds[wrr * XSTR + wch + 8] = v1;
    }
    if (cc < 7) {   // prefetch next chunk; stays in flight across MFMA
      const int c2 = (cc + 1) * 32;
      #pragma unroll
      for (int i = 0; i < 4; i++)
        xr[i] = *(const floatx4*)(C.x + (size_t)(b * CB + c2 + xc0 + i) * HW + pos0 + xp0);
      const float* wp = C.w + (size_t)wrr * C.wstride + c2 + wch;
      if (walign) {
        #pragma unroll
        for (int i = 0; i < 4; i++) ww4[i] = *(const floatx4*)(wp + i * 4);
      } else {
        #pragma unroll
        for (int i = 0; i < 4; i++)
          #pragma unroll
          for (int jj = 0; jj < 4; jj++) ww4[i][jj] = wp[i * 4 + jj];
      }
    }
    barrier_nodrain();   // tile visible (lgkm only, vmcnt alive)
    if (!C.transposed) {
      half8 a0 = as_h8(*(const uintx4*)&w_lds[(mbase + ln16) * XSTR + quad * 8]);
      half8 a1 = as_h8(*(const uintx4*)&w_lds[(mbase + 16 + ln16) * XSTR + quad * 8]);
      #pragma unroll
      for (int nt = 0; nt < 8; nt++) {
        half8 bf = as_h8(*(const uintx4*)&x_lds[(nt * 16 + ln16) * XSTR + quad * 8]);
        acc[0][nt] = __builtin_amdgcn_mfma_f32_16x16x32_f16(a0, bf, acc[0][nt], 0, 0, 0);
        acc[1][nt] = __builtin_amdgcn_mfma_f32_16x16x32_f16(a1, bf, acc[1][nt], 0, 0, 0);
      }
    } else {
      half8 a0 = as_h8(*(const uintx4*)&x_lds[(mbase + ln16) * XSTR + quad * 8]);
      half8 a1 = as_h8(*(const uintx4*)&x_lds[(mbase + 16 + ln16) * XSTR + quad * 8]);
      #pragma unroll
      for (int nt = 0; nt < 8; nt++) {
        half8 bf = as_h8(*(const uintx4*)&w_lds[(nt * 16 + ln16) * XSTR + quad * 8]);
        acc[0][nt] = __builtin_amdgcn_mfma_f32_16x16x32_f16(a0, bf, acc[0][nt], 0, 0, 0);
        acc[1][nt] = __builtin_amdgcn_mfma_f32_16x16x32_f16(a1, bf, acc[1][nt], 0, 0, 0);
      }
    }
  }

  if (!C.transposed) {
    #pragma unroll
    for (int mt = 0; mt < 2; mt++) {
      const int r0 = mbase + mt * 16 + quad * 4;
      floatx4 bi = *(const floatx4*)(C.bias + r0);
      float wc[4];
      if (C.pre) {
        #pragma unroll
        for (int rr = 0; rr < 4; rr++) wc[rr] = C.w[(size_t)(r0 + rr) * C.wstride + 256];
      }
      #pragma unroll
      for (int nt = 0; nt < 8; nt++) {
        const int pos = pos0 + nt * 16 + ln16;
        floatx4 v = acc[mt][nt];
        #pragma unroll
        for (int rr = 0; rr < 4; rr++) v[rr] += bi[rr];
        if (C.pre) {
          const float pv = C.pre[(size_t)b * HW + pos] * (1.f / 128.f);
          #pragma unroll
          for (int rr = 0; rr < 4; rr++) v[rr] += pv * wc[rr];
        }
        if (C.add) {
          #pragma unroll
          for (int rr = 0; rr < 4; rr++)
            v[rr] += C.add[(size_t)(b * RP + r0 + rr) * HW + pos];
        }
        Pk4 pk;
        #pragma unroll
        for (int rr = 0; rr < 4; rr++) pk.u[rr] = f2h(v[rr]);
        *(uintx2*)(C.out + (size_t)(b * HW + pos) * RP + r0) = pk.v;
      }
    }
  } else {
    #pragma unroll
    for (int nt = 0; nt < 8; nt++) {
      const int r = nt * 16 + ln16;
      const float bs = C.bias[r];
      #pragma unroll
      for (int mt = 0; mt < 2; mt++) {
        const int pv = pos0 + mbase + mt * 16 + quad * 4;
        floatx4 v = acc[mt][nt];
        Pk4 pk;
        #pragma unroll
        for (int rr = 0; rr < 4; rr++) pk.u[rr] = f2h(v[rr] + bs);
        *(uintx2*)(C.out + (size_t)(b * RP + r) * HW + pv) = pk.v;
      }
    }
  }
}

// ---------------------------------------------------------------------------
// Flash attention (R15): no split-K, XCD-group swizzle, colones l/aC MFMA,
// P through per-wave LDS (verified-correct path).
// ---------------------------------------------------------------------------
__global__ __launch_bounds__(256) void ra_flash(
    const u16* __restrict__ thetaL, const u16* __restrict__ phiTL,
    const u16* __restrict__ gTL,
    const u16* __restrict__ thetaR, const u16* __restrict__ phiTR,
    const u16* __restrict__ gTR,
    u16* __restrict__ afterL, u16* __restrict__ afterR,
    float* __restrict__ idxL, float* __restrict__ idxR)
{
  __shared__ uintx4 phi_lds[16 * 65];   // [rchunk8 cb(16)][k(64)]
  __shared__ uintx4 g_lds[8 * 129];     // [kchunk8 kcb(8)][v(128)]
  __shared__ u16 P_lds[4][16 * 76];     // per-wave [q(16)][k(64)], stride 76

  const int tid  = threadIdx.x;
  const int h    = blockIdx.x;
  const int bx   = ((h & 7) << 6) | (h >> 3);   // XCD-group swizzle (512 = 8x64)
  const int side = bx >> 8;
  const int sbx  = bx & 255;
  const u16* __restrict__ theta = side ? thetaR : thetaL;
  const u16* __restrict__ phiT  = side ? phiTR  : phiTL;
  const u16* __restrict__ gT    = side ? gTR    : gTL;

  const int b    = sbx >> 6;
  const int q0   = (sbx & 63) * 64;
  const int wv   = tid >> 6;
  const int lane = tid & 63;
  const int ln16 = lane & 15;
  const int quad = lane >> 4;

  uintx4 aq[4];
  {
    const uintx4* tr = (const uintx4*)(theta + (size_t)(b * HW + q0 + wv * 16 + ln16) * RP);
    #pragma unroll
    for (int c = 0; c < 4; c++) aq[c] = tr[c * 4 + quad];
  }

  // colones A-fragment: row0 = k-in-tile (0..63), row1 = 1, rows 2..15 = 0.
  half8 cf0, cf1;
  {
    #pragma unroll
    for (int i = 0; i < 8; i++) {
      float c0 = (ln16 == 0) ? (float)(quad * 8 + i)      : (ln16 == 1 ? 1.f : 0.f);
      float c1 = (ln16 == 0) ? (float)(32 + quad * 8 + i) : (ln16 == 1 ? 1.f : 0.f);
      cf0[i] = (_Float16)c0;
      cf1[i] = (_Float16)c1;
    }
  }

  floatx4 accO[8];
  #pragma unroll
  for (int v = 0; v < 8; v++) accO[v] = (floatx4)0.0f;
  floatx4 accE  = (floatx4)0.0f;   // even-j: [0]=Σp·kk, [1]=Σp (quad0 rows)
  floatx4 accEo = (floatx4)0.0f;   // odd-j
  float m_q = -3.0e38f;

  const int sk  = tid >> 4, scb = tid & 15;  // phi staging
  const int gv_ = tid >> 3, gcb = tid & 7;   // g staging

  uintx4 sp[4], sg[4];
  #pragma unroll
  for (int i = 0; i < 4; i++) {
    sp[i] = *(const uintx4*)(phiT + (size_t)(b * HW + i * 16 + sk) * RP + scb * 8);
    sg[i] = *(const uintx4*)(gT + (size_t)(b * RP + i * 32 + gv_) * HW + gcb * 8);
  }

  #pragma unroll 1
  for (int j = 0; j < 64; j++) {
    #pragma unroll
    for (int i = 0; i < 4; i++) {
      phi_lds[scb * 65 + i * 16 + sk] = sp[i];
      g_lds[gcb * 129 + i * 32 + gv_] = sg[i];
    }
    if (j < 63) {
      const int k0n = (j + 1) * 64;
      #pragma unroll
      for (int i = 0; i < 4; i++) {
        sp[i] = *(const uintx4*)(phiT + (size_t)(b * HW + k0n + i * 16 + sk) * RP + scb * 8);
        sg[i] = *(const uintx4*)(gT + (size_t)(b * RP + i * 32 + gv_) * HW + k0n + gcb * 8);
      }
    }
    barrier_nodrain();

    floatx4 sf[4];
    #pragma unroll
    for (int s = 0; s < 4; s++) sf[s] = (floatx4)0.0f;
    __builtin_amdgcn_s_setprio(1);
    #pragma unroll
    for (int c = 0; c < 4; c++) {
      half8 bth = as_h8(aq[c]);
      #pragma unroll
      for (int s = 0; s < 4; s++) {
        uintx4 ap = phi_lds[(c * 4 + quad) * 65 + s * 16 + ln16];
        sf[s] = __builtin_amdgcn_mfma_f32_16x16x32_f16(as_h8(ap), bth, sf[s], 0, 0, 0);
      }
    }
    __builtin_amdgcn_s_setprio(0);

    float ms0 = fmaxf(fmaxf(sf[0][0], sf[0][1]), fmaxf(sf[0][2], sf[0][3]));
    float ms1 = fmaxf(fmaxf(sf[1][0], sf[1][1]), fmaxf(sf[1][2], sf[1][3]));
    float ms2 = fmaxf(fmaxf(sf[2][0], sf[2][1]), fmaxf(sf[2][2], sf[2][3]));
    float ms3 = fmaxf(fmaxf(sf[3][0], sf[3][1]), fmaxf(sf[3][2], sf[3][3]));
    float mx = fmaxf(fmaxf(ms0, ms1), fmaxf(ms2, ms3));
    mx = fmaxf(mx, __shfl_xor(mx, 16));
    mx = fmaxf(mx, __shfl_xor(mx, 32));
    if (__any(mx > m_q + 8.f)) {       // wave-uniform, rare in steady state
      const float mnew  = fmaxf(m_q, mx);
      const float alpha = __expf(m_q - mnew);
      m_q = mnew;
      accE *= alpha; accEo *= alpha;
      #pragma unroll
      for (int v = 0; v < 8; v++) accO[v] *= alpha;
    }
    #pragma unroll
    for (int s = 0; s < 4; s++) {
      float p0 = __expf(sf[s][0] - m_q);
      float p1 = __expf(sf[s][1] - m_q);
      float p2 = __expf(sf[s][2] - m_q);
      float p3 = __expf(sf[s][3] - m_q);
      uintx2 pkv;
      pkv[0] = pkrtz(p0, p1);
      pkv[1] = pkrtz(p2, p3);
      *(uintx2*)&P_lds[wv][ln16 * 76 + s * 16 + quad * 4] = pkv;
    }

    // no barrier: P_lds is wave-private; DS ops in-order per wave.
    half8 pb0 = as_h8(*(const uintx4*)&P_lds[wv][ln16 * 76 + quad * 8]);
    half8 pb1 = as_h8(*(const uintx4*)&P_lds[wv][ln16 * 76 + 32 + quad * 8]);
    __builtin_amdgcn_s_setprio(1);
    #pragma unroll
    for (int vt = 0; vt < 8; vt++) {
      uintx4 ag0 = g_lds[quad * 129 + vt * 16 + ln16];
      uintx4 ag1 = g_lds[(4 + quad) * 129 + vt * 16 + ln16];
      accO[vt] = __builtin_amdgcn_mfma_f32_16x16x32_f16(as_h8(ag0), pb0, accO[vt], 0, 0, 0);
      accO[vt] = __builtin_amdgcn_mfma_f32_16x16x32_f16(as_h8(ag1), pb1, accO[vt], 0, 0, 0);
    }
    if (j & 1) {
      accEo = __builtin_amdgcn_mfma_f32_16x16x32_f16(cf0, pb0, accEo, 0, 0, 0);
      accEo = __builtin_amdgcn_mfma_f32_16x16x32_f16(cf1, pb1, accEo, 0, 0, 0);
    } else {
      accE  = __builtin_amdgcn_mfma_f32_16x16x32_f16(cf0, pb0, accE, 0, 0, 0);
      accE  = __builtin_amdgcn_mfma_f32_16x16x32_f16(cf1, pb1, accE, 0, 0, 0);
    }
    __builtin_amdgcn_s_setprio(0);
    barrier_nodrain();
  }

  // epilogue: l = Σp (all j), aC = Σp·kk + 64·Σp(odd j); broadcast via shfl.
  const float l0 = accE[1] + accEo[1];
  const float a0 = accE[0] + accEo[0] + 64.f * accEo[1];
  const float l_all  = __shfl(l0, ln16);
  const float aC_all = __shfl(a0, ln16);

  const int q = q0 + wv * 16 + ln16;
  const size_t p = (size_t)b * HW + q;
  u16* after = side ? afterR : afterL;
  u16* orow = after + p * RP;
  const float invl = 1.f / l_all;
  #pragma unroll
  for (int vt = 0; vt < 8; vt++) {
    uintx2 pkv;
    pkv[0] = pkrtz(accO[vt][0] * invl, accO[vt][1] * invl);
    pkv[1] = pkrtz(accO[vt][2] * invl, accO[vt][3] * invl);
    *(uintx2*)(orow + vt * 16 + quad * 4) = pkv;
  }
  if (quad == 0) {
    float* idx = side ? idxR : idxL;
    idx[p] = (float)(q & 127) - aC_all * invl;
  }
}

// ---------------------------------------------------------------------------
// Up-projection stats only (R15 + XCD swizzle): MFMA y, Σy/Σy² atomics.
// ---------------------------------------------------------------------------
#define WSTR 136   // u16 stride (272B, 16B-aligned rows)

__global__ __launch_bounds__(256) void ra_upstats(
    const u16* __restrict__ afterL, const u16* __restrict__ afterR,
    const float* __restrict__ w, const float* __restrict__ bias,
    float* __restrict__ stL, float* __restrict__ stR)
{
  __shared__ u16 w_lds[128 * WSTR];   // [co][r]; reused as float scratch
  const int tid  = threadIdx.x;
  const int h    = blockIdx.x;
  const int bx   = ((h & 7) << 6) | (h >> 3);   // XCD-group swizzle (512 = 8x64)
  const int side = bx >> 8;
  const int sbx  = bx & 255;
  const u16* __restrict__ after = side ? afterR : afterL;
  const int b    = sbx >> 6;
  const int pos0 = ((sbx >> 1) & 31) * 128;
  const int hc   = sbx & 1;
  const int wv   = tid >> 6;
  const int lane = tid & 63;
  const int ln16 = lane & 15;
  const int quad = lane >> 4;

  {
    const int co = tid >> 1, rh = (tid & 1) * 64;
    const float* wp = w + (size_t)(hc * 128 + co) * RP + rh;
    #pragma unroll
    for (int i = 0; i < 8; i++) {
      floatx4 f0 = *(const floatx4*)(wp + i * 8);
      floatx4 f1 = *(const floatx4*)(wp + i * 8 + 4);
      uintx4 v;
      v[0] = pk2h(f0[0], f0[1]); v[1] = pk2h(f0[2], f0[3]);
      v[2] = pk2h(f1[0], f1[1]); v[3] = pk2h(f1[2], f1[3]);
      *(uintx4*)&w_lds[co * WSTR + rh + i * 8] = v;
    }
  }
  __syncthreads();

  floatx4 acc[2][8];
  #pragma unroll
  for (int mt = 0; mt < 2; mt++)
    #pragma unroll
    for (int nt = 0; nt < 8; nt++) acc[mt][nt] = (floatx4)0.0f;

  #pragma unroll
  for (int kk = 0; kk < 4; kk++) {
    half8 a[2];
    #pragma unroll
    for (int mt = 0; mt < 2; mt++)
      a[mt] = as_h8(*(const uintx4*)(after +
          (size_t)(b * HW + pos0 + wv * 32 + mt * 16 + ln16) * RP + kk * 32 + quad * 8));
    #pragma unroll
    for (int nt = 0; nt < 8; nt++) {
      half8 bf = as_h8(*(const uintx4*)&w_lds[(nt * 16 + ln16) * WSTR + kk * 32 + quad * 8]);
      acc[0][nt] = __builtin_amdgcn_mfma_f32_16x16x32_f16(a[0], bf, acc[0][nt], 0, 0, 0);
      acc[1][nt] = __builtin_amdgcn_mfma_f32_16x16x32_f16(a[1], bf, acc[1][nt], 0, 0, 0);
    }
  }

  // per-channel partials (this block: 128 pos of one b)
  float s_nt[8], q_nt[8];
  #pragma unroll
  for (int nt = 0; nt < 8; nt++) {
    const float bs = bias[hc * 128 + nt * 16 + ln16];
    float s = 0.f, sq = 0.f;
    #pragma unroll
    for (int mt = 0; mt < 2; mt++) {
      #pragma unroll
      for (int rr = 0; rr < 4; rr++) {
        const float yv = acc[mt][nt][rr] + bs;
        s += yv; sq += yv * yv;
      }
    }
    s  += __shfl_xor(s, 16);  s  += __shfl_xor(s, 32);
    sq += __shfl_xor(sq, 16); sq += __shfl_xor(sq, 32);
    s_nt[nt] = s; q_nt[nt] = sq;
  }
  __syncthreads();              // all waves done reading w_lds
  float* scr = (float*)w_lds;   // [0..511]=s per (wv,co), [512..1023]=sq
  if (quad == 0) {
    #pragma unroll
    for (int nt = 0; nt < 8; nt++) {
      scr[wv * 128 + nt * 16 + ln16]       = s_nt[nt];
      scr[512 + wv * 128 + nt * 16 + ln16] = q_nt[nt];
    }
  }
  __syncthreads();
  if (tid < 128) {
    const float s  = scr[tid] + scr[128 + tid] + scr[256 + tid] + scr[384 + tid];
    const float sq = scr[512 + tid] + scr[640 + tid] + scr[768 + tid] + scr[896 + tid];
    float* stats = side ? stR : stL;
    atomicAdd(&stats[2 * (hc * 128 + tid)], s);
    atomicAdd(&stats[2 * (hc * 128 + tid) + 1], sq);
  }
}

// ---------------------------------------------------------------------------
// Fused up-projection + batch-norm + residual (R15 + XCD swizzle).
// ---------------------------------------------------------------------------
__global__ __launch_bounds__(256) void ra_finm(
    const u16* __restrict__ afterL, const u16* __restrict__ afterR,
    const float* __restrict__ w, const float* __restrict__ bias,
    const float* __restrict__ left, const float* __restrict__ right,
    const float* __restrict__ stL, const float* __restrict__ stR,
    const float* __restrict__ gamma, const float* __restrict__ beta,
    float* __restrict__ out)
{
  __shared__ u16 w_lds[128 * WSTR];   // [co][r]
  const int tid  = threadIdx.x;
  const int h    = blockIdx.x;
  const int bx   = ((h & 7) << 6) | (h >> 3);   // XCD-group swizzle (512 = 8x64)
  const int side = bx >> 8;
  const int sbx  = bx & 255;
  const u16* __restrict__ after = side ? afterR : afterL;
  const int b    = sbx >> 6;
  const int pos0 = ((sbx >> 1) & 31) * 128;
  const int hc   = sbx & 1;
  const int wv   = tid >> 6;
  const int lane = tid & 63;
  const int ln16 = lane & 15;
  const int quad = lane >> 4;

  {
    const int co = tid >> 1, rh = (tid & 1) * 64;
    const float* wp = w + (size_t)(hc * 128 + co) * RP + rh;
    #pragma unroll
    for (int i = 0; i < 8; i++) {
      floatx4 f0 = *(const floatx4*)(wp + i * 8);
      floatx4 f1 = *(const floatx4*)(wp + i * 8 + 4);
      uintx4 v;
      v[0] = pk2h(f0[0], f0[1]); v[1] = pk2h(f0[2], f0[3]);
      v[2] = pk2h(f1[0], f1[1]); v[3] = pk2h(f1[2], f1[3]);
      *(uintx4*)&w_lds[co * WSTR + rh + i * 8] = v;
    }
  }
  __syncthreads();

  floatx4 acc[2][8];
  #pragma unroll
  for (int mt = 0; mt < 2; mt++)
    #pragma unroll
    for (int nt = 0; nt < 8; nt++) acc[mt][nt] = (floatx4)0.0f;

  #pragma unroll
  for (int kk = 0; kk < 4; kk++) {
    half8 a[2];
    #pragma unroll
    for (int mt = 0; mt < 2; mt++)
      a[mt] = as_h8(*(const uintx4*)(after +
          (size_t)(b * HW + pos0 + wv * 32 + mt * 16 + ln16) * RP + kk * 32 + quad * 8));
    #pragma unroll
    for (int nt = 0; nt < 8; nt++) {
      half8 bf = as_h8(*(const uintx4*)&w_lds[(nt * 16 + ln16) * WSTR + kk * 32 + quad * 8]);
      acc[0][nt] = __builtin_amdgcn_mfma_f32_16x16x32_f16(a[0], bf, acc[0][nt], 0, 0, 0);
      acc[1][nt] = __builtin_amdgcn_mfma_f32_16x16x32_f16(a[1], bf, acc[1][nt], 0, 0, 0);
    }
  }

  const float* x = side ? right : left;
  const float* stats = side ? stR : stL;
  float* outs = out + (size_t)side * 4194304;
  #pragma unroll
  for (int nt = 0; nt < 8; nt++) {
    const int co = hc * 128 + nt * 16 + ln16;
    const float s = stats[2 * co], sq = stats[2 * co + 1];
    const float mean = s * (1.f / 16384.f);
    const float var  = sq * (1.f / 16384.f) - mean * mean;
    const float rstd = rsqrtf(var + EPSF);
    const float ga = gamma[co], be = beta[co];
    const float bs = bias[co];
    #pragma unroll
    for (int mt = 0; mt < 2; mt++) {
      const int pv = pos0 + wv * 32 + mt * 16 + quad * 4;
      floatx4 xv = *(const floatx4*)(x + (size_t)(b * CB + co) * HW + pv);
      floatx4 o;
      #pragma unroll
      for (int rr = 0; rr < 4; rr++) {
        const float yv = acc[mt][nt][rr] + bs;
        o[rr] = xv[rr] + ga * ((yv - mean) * rstd) + be;
      }
      *(floatx4*)(outs + (size_t)(b * CB + co) * HW + pv) = o;
    }
  }
}

// ---------------------------------------------------------------------------
extern "C" void kernel_launch(void* const* d_in, const int* in_sizes, int n_in,
                              void* d_out, int out_size, void* d_ws, size_t ws_size,
                              hipStream_t stream)
{
  const float* left    = (const float*)d_in[0];
  const float* right   = (const float*)d_in[1];
  const float* pre_l   = (const float*)d_in[2];
  const float* pre_r   = (const float*)d_in[3];
  const float* query_l = (const float*)d_in[4];
  const float* key_l   = (const float*)d_in[5];
  const float* query_r = (const float*)d_in[6];
  const float* key_r   = (const float*)d_in[7];
  const float* theta_w = (const float*)d_in[8];
  const float* theta_b = (const float*)d_in[9];
  const float* phi_w   = (const float*)d_in[10];
  const float* phi_b   = (const float*)d_in[11];
  const float* g_w     = (const float*)d_in[12];
  const float* g_b     = (const float*)d_in[13];
  const float* up_w    = (const float*)d_in[14];
  const float* up_b    = (const float*)d_in[15];
  const float* bn_g    = (const float*)d_in[16];
  const float* bn_b    = (const float*)d_in[17];
  float* out = (float*)d_out;

  char* ws = (char*)d_ws;
  const size_t SZ = (size_t)4 * HW * RP * 2;  // 4 MiB (fp16 [4][4096][128])
  u16* thetaL = (u16*)(ws);
  u16* phiTL  = (u16*)(ws + 1 * SZ);
  u16* gTL    = (u16*)(ws + 2 * SZ);
  u16* thetaR = (u16*)(ws + 3 * SZ);
  u16* phiTR  = (u16*)(ws + 4 * SZ);
  u16* gTR    = (u16*)(ws + 5 * SZ);
  u16* afterL = (u16*)(ws + 6 * SZ);
  u16* afterR = (u16*)(ws + 7 * SZ);
  float* stL  = (float*)(ws + 8 * SZ);
  float* stR  = (float*)(ws + 8 * SZ + 2048);

  dim3 blk(256);
  // side L: x_q=left, x_kv=right, query_l, key_r; side R mirrored.
  ProjCfg6 pc;
  pc.c[0] = { left,  theta_w, theta_b, query_l, pre_l,   thetaL, 257, 0 };
  pc.c[1] = { right, phi_w,   phi_b,   key_r,   nullptr, phiTL,  256, 0 };
  pc.c[2] = { right, g_w,     g_b,     nullptr, nullptr, gTL,    256, 1 };
  pc.c[3] = { right, theta_w, theta_b, query_r, pre_r,   thetaR, 257, 0 };
  pc.c[4] = { left,  phi_w,   phi_b,   key_l,   nullptr, phiTR,  256, 0 };
  pc.c[5] = { left,  g_w,     g_b,     nullptr, nullptr, gTR,    256, 1 };
  ra_projm<<<768, blk, 0, stream>>>(pc, stL);

  ra_flash<<<512, blk, 0, stream>>>(thetaL, phiTL, gTL, thetaR, phiTR, gTR,
                                    afterL, afterR,
                                    out + 8388608, out + 8404992);
  ra_upstats<<<512, blk, 0, stream>>>(afterL, afterR, up_w, up_b, stL, stR);
  ra_finm<<<512, blk, 0, stream>>>(afterL, afterR, up_w, up_b, left, right,
                                   stL, stR, bn_g, bn_b, out);

  (void)in_sizes; (void)n_in; (void)out_size; (void)ws_size;
}

// Round 14
// 309.455 us; speedup vs baseline: 1.0143x; 1.0006x over previous
//
#include <hip/hip_runtime.h>

// row_attention_maxindex on MI355X — R18: in-register P routing, take 2.
// R16's derivation re-verified element-wise (route is correct on paper);
// failure attributed to raw inline-asm (no hazard handling). This round
// uses the verified builtins __builtin_amdgcn_permlane{32,16}_swap.
// P_lds deleted: flash LDS 43->33KB, -6 LDS ops/wave-iter, no serial
// DS write->read wait. Rest identical to R17 (309.6us, passed).

typedef unsigned short u16;
typedef unsigned int   u32;
typedef float        floatx4 __attribute__((ext_vector_type(4)));
typedef unsigned int uintx4  __attribute__((ext_vector_type(4)));
typedef unsigned int uintx2  __attribute__((ext_vector_type(2)));
typedef _Float16     half8   __attribute__((ext_vector_type(8)));
typedef __fp16       fp16x2  __attribute__((ext_vector_type(2)));

#define HW 4096
#define CB 256
#define RP 128
#define EPSF 1e-5f

static __device__ __forceinline__ u16 f2bf(float f) {
  u32 u = __float_as_uint(f);
  u32 r = u + 0x7FFFu + ((u >> 16) & 1u);   // RNE
  return (u16)(r >> 16);
}
static __device__ __forceinline__ float bf2f(u16 h) {
  return __uint_as_float(((u32)h) << 16);
}
static __device__ __forceinline__ u16 f2h(float f) {
  _Float16 h = (_Float16)f;                 // RNE
  return __builtin_bit_cast(u16, h);
}
static __device__ __forceinline__ float h2f(u16 h) {
  return (float)__builtin_bit_cast(_Float16, h);
}
static __device__ __forceinline__ half8 as_h8(uintx4 v) {
  return __builtin_bit_cast(half8, v);
}
static __device__ __forceinline__ u32 pkrtz(float a, float b) {
  fp16x2 h = __builtin_amdgcn_cvt_pkrtz(a, b);
  return __builtin_bit_cast(u32, h);
}
static __device__ __forceinline__ u32 pk2h(float a, float b) {  // RNE pair
  return (u32)f2h(a) | ((u32)f2h(b) << 16);
}
// Barrier with DS-visibility only: does NOT drain vmcnt.
static __device__ __forceinline__ void barrier_nodrain() {
  __builtin_amdgcn_sched_barrier(0);
  asm volatile("s_waitcnt lgkmcnt(0)" ::: "memory");
  __builtin_amdgcn_s_barrier();
  __builtin_amdgcn_sched_barrier(0);
}
// Route (A_s, A_{s+1}) packed P-pairs into PV B-fragment words via the
// gfx950 permlane swap builtins (VALU, no LDS). After P32+P16:
//   a = rows (a.r0, b.r0, a.r2, b.r2)  -> keys (8q+off, 8q+off+1)
//   b = rows (a.r1, b.r1, a.r3, b.r3)  -> keys (8q+4+off, 8q+5+off)
static __device__ __forceinline__ void route_p(u32& a, u32& b) {
  uintx2 t = __builtin_amdgcn_permlane32_swap(a, b, false, false);
  uintx2 u = __builtin_amdgcn_permlane16_swap(t[0], t[1], false, false);
  a = u[0]; b = u[1];
}

union Pk4 { u16 u[4]; uintx2 v; };

// ---------------------------------------------------------------------------
// MFMA mega-projection: 6 projections, blockIdx>>7 selects config. (R14)
// ---------------------------------------------------------------------------
struct ProjCfg {
  const float* x; const float* w; const float* bias;
  const float* add; const float* pre; u16* out;
  int wstride; int transposed;
};
struct ProjCfg6 { ProjCfg c[6]; };

#define XSTR 40   // u16 stride of [128][32] fp16 LDS tiles

__global__ __launch_bounds__(256) void ra_projm(ProjCfg6 cfg, float* stz)
{
  __shared__ u16 x_lds[128 * XSTR];   // [pos][c32]
  __shared__ u16 w_lds[128 * XSTR];   // [r][c32]
  if (blockIdx.x == 0) {              // zero stats accumulators (1024 floats)
    ((floatx4*)stz)[threadIdx.x] = (floatx4)0.0f;
  }
  const ProjCfg C = cfg.c[blockIdx.x >> 7];
  const int inner = blockIdx.x & 127;       // b(4) x posb(32)
  const int b    = inner >> 5;
  const int pos0 = (inner & 31) * 128;
  const int tid  = threadIdx.x;
  const int wv   = tid >> 6;
  const int lane = tid & 63;
  const int ln16 = lane & 15;
  const int quad = lane >> 4;
  const int mbase = wv * 32;

  const int xc0 = (tid & 7) * 4, xp0 = (tid >> 3) * 4;   // x: 4c x 4pos
  const int wrr = tid >> 1, wch = (tid & 1) * 16;        // w: 1r x 16c
  const bool walign = (C.wstride & 3) == 0;

  floatx4 acc[2][8];
  #pragma unroll
  for (int mt = 0; mt < 2; mt++)
    #pragma unroll
    for (int nt = 0; nt < 8; nt++) acc[mt][nt] = (floatx4)0.0f;

  floatx4 xr[4];
  floatx4 ww4[4];
  {
    #pragma unroll
    for (int i = 0; i < 4; i++)
      xr[i] = *(const floatx4*)(C.x + (size_t)(b * CB + xc0 + i) * HW + pos0 + xp0);
    const float* wp = C.w + (size_t)wrr * C.wstride + wch;
    if (walign) {
      #pragma unroll
      for (int i = 0; i < 4; i++) ww4[i] = *(const floatx4*)(wp + i * 4);
    } else {
      #pragma unroll
      for (int i = 0; i < 4; i++)
        #pragma unroll
        for (int jj = 0; jj < 4; jj++) ww4[i][jj] = wp[i * 4 + jj];
    }
  }

  #pragma unroll 1
  for (int cc = 0; cc < 8; ++cc) {
    barrier_nodrain();   // prev chunk's LDS reads complete -> safe overwrite
    #pragma unroll
    for (int pp = 0; pp < 4; pp++) {
      uintx2 v;
      v[0] = pk2h(xr[0][pp], xr[1][pp]);
      v[1] = pk2h(xr[2][pp], xr[3][pp]);
      *(uintx2*)&x_lds[(xp0 + pp) * XSTR + xc0] = v;
    }
    {
      uintx4 v0, v1;
      v0[0] = pk2h(ww4[0][0], ww4[0][1]); v0[1] = pk2h(ww4[0][2], ww4[0][3]);
      v0[2] = pk2h(ww4[1][0], ww4[1][1]); v0[3] = pk2h(ww4[1][2], ww4[1][3]);
      v1[0] = pk2h(ww4[2][0], ww4[2][1]); v1[1] = pk2h(ww4[2][2], ww4[2][3]);
      v1[2] = pk2h(ww4[3][0], ww4[3][1]); v1[3] = pk2h(ww4[3][2], ww4[3][3]);
      *(uintx4*)&w_lds[wrr * XSTR + wch]     = v0;
      *(uintx4*)&w_lds[wrr * XSTR + wch + 8] = v1;
    }
    if (cc < 7) {   // prefetch next chunk; stays in flight across MFMA
      const int c2 = (cc + 1) * 32;
      #pragma unroll
      for (int i = 0; i < 4; i++)
        xr[i] = *(const floatx4*)(C.x + (size_t)(b * CB + c2 + xc0 + i) * HW + pos0 + xp0);
      const float* wp = C.w + (size_t)wrr * C.wstride + c2 + wch;
      if (walign) {
        #pragma unroll
        for (int i = 0; i < 4; i++) ww4[i] = *(const floatx4*)(wp + i * 4);
      } else {
        #pragma unroll
        for (int i = 0; i < 4; i++)
          #pragma unroll
          for (int jj = 0; jj < 4; jj++) ww4[i][jj] = wp[i * 4 + jj];
      }
    }
    barrier_nodrain();   // tile visible (lgkm only, vmcnt alive)
    if (!C.transposed) {
      half8 a0 = as_h8(*(const uintx4*)&w_lds[(mbase + ln16) * XSTR + quad * 8]);
      half8 a1 = as_h8(*(const uintx4*)&w_lds[(mbase + 16 + ln16) * XSTR + quad * 8]);
      #pragma unroll
      for (int nt = 0; nt < 8; nt++) {
        half8 bf = as_h8(*(const uintx4*)&x_lds[(nt * 16 + ln16) * XSTR + quad * 8]);
        acc[0][nt] = __builtin_amdgcn_mfma_f32_16x16x32_f16(a0, bf, acc[0][nt], 0, 0, 0);
        acc[1][nt] = __builtin_amdgcn_mfma_f32_16x16x32_f16(a1, bf, acc[1][nt], 0, 0, 0);
      }
    } else {
      half8 a0 = as_h8(*(const uintx4*)&x_lds[(mbase + ln16) * XSTR + quad * 8]);
      half8 a1 = as_h8(*(const uintx4*)&x_lds[(mbase + 16 + ln16) * XSTR + quad * 8]);
      #pragma unroll
      for (int nt = 0; nt < 8; nt++) {
        half8 bf = as_h8(*(const uintx4*)&w_lds[(nt * 16 + ln16) * XSTR + quad * 8]);
        acc[0][nt] = __builtin_amdgcn_mfma_f32_16x16x32_f16(a0, bf, acc[0][nt], 0, 0, 0);
        acc[1][nt] = __builtin_amdgcn_mfma_f32_16x16x32_f16(a1, bf, acc[1][nt], 0, 0, 0);
      }
    }
  }

  if (!C.transposed) {
    #pragma unroll
    for (int mt = 0; mt < 2; mt++) {
      const int r0 = mbase + mt * 16 + quad * 4;
      floatx4 bi = *(const floatx4*)(C.bias + r0);
      float wc[4];
      if (C.pre) {
        #pragma unroll
        for (int rr = 0; rr < 4; rr++) wc[rr] = C.w[(size_t)(r0 + rr) * C.wstride + 256];
      }
      #pragma unroll
      for (int nt = 0; nt < 8; nt++) {
        const int pos = pos0 + nt * 16 + ln16;
        floatx4 v = acc[mt][nt];
        #pragma unroll
        for (int rr = 0; rr < 4; rr++) v[rr] += bi[rr];
        if (C.pre) {
          const float pv = C.pre[(size_t)b * HW + pos] * (1.f / 128.f);
          #pragma unroll
          for (int rr = 0; rr < 4; rr++) v[rr] += pv * wc[rr];
        }
        if (C.add) {
          #pragma unroll
          for (int rr = 0; rr < 4; rr++)
            v[rr] += C.add[(size_t)(b * RP + r0 + rr) * HW + pos];
        }
        Pk4 pk;
        #pragma unroll
        for (int rr = 0; rr < 4; rr++) pk.u[rr] = f2h(v[rr]);
        *(uintx2*)(C.out + (size_t)(b * HW + pos) * RP + r0) = pk.v;
      }
    }
  } else {
    #pragma unroll
    for (int nt = 0; nt < 8; nt++) {
      const int r = nt * 16 + ln16;
      const float bs = C.bias[r];
      #pragma unroll
      for (int mt = 0; mt < 2; mt++) {
        const int pv = pos0 + mbase + mt * 16 + quad * 4;
        floatx4 v = acc[mt][nt];
        Pk4 pk;
        #pragma unroll
        for (int rr = 0; rr < 4; rr++) pk.u[rr] = f2h(v[rr] + bs);
        *(uintx2*)(C.out + (size_t)(b * RP + r) * HW + pv) = pk.v;
      }
    }
  }
}

// ---------------------------------------------------------------------------
// Flash attention (R17 structure + permlane P routing, no P_lds).
// 512 blocks = 8 (side,b) groups x 64 q-tiles, XCD-group swizzled.
// ---------------------------------------------------------------------------
__global__ __launch_bounds__(256) void ra_flash(
    const u16* __restrict__ thetaL, const u16* __restrict__ phiTL,
    const u16* __restrict__ gTL,
    const u16* __restrict__ thetaR, const u16* __restrict__ phiTR,
    const u16* __restrict__ gTR,
    u16* __restrict__ afterL, u16* __restrict__ afterR,
    float* __restrict__ idxL, float* __restrict__ idxR)
{
  __shared__ uintx4 phi_lds[16 * 65];   // [rchunk8 cb(16)][k(64)]
  __shared__ uintx4 g_lds[8 * 129];     // [kchunk8 kcb(8)][v(128)]

  const int tid  = threadIdx.x;
  const int h    = blockIdx.x;
  const int bx   = ((h & 7) << 6) | (h >> 3);   // XCD-group swizzle (512 = 8x64)
  const int side = bx >> 8;
  const int sbx  = bx & 255;
  const u16* __restrict__ theta = side ? thetaR : thetaL;
  const u16* __restrict__ phiT  = side ? phiTR  : phiTL;
  const u16* __restrict__ gT    = side ? gTR    : gTL;

  const int b    = sbx >> 6;
  const int q0   = (sbx & 63) * 64;
  const int wv   = tid >> 6;
  const int lane = tid & 63;
  const int ln16 = lane & 15;
  const int quad = lane >> 4;

  uintx4 aq[4];
  {
    const uintx4* tr = (const uintx4*)(theta + (size_t)(b * HW + q0 + wv * 16 + ln16) * RP);
    #pragma unroll
    for (int c = 0; c < 4; c++) aq[c] = tr[c * 4 + quad];
  }

  // colones A-fragment: row0 = k-in-tile (0..63), row1 = 1, rows 2..15 = 0.
  half8 cf0, cf1;
  {
    #pragma unroll
    for (int i = 0; i < 8; i++) {
      float c0 = (ln16 == 0) ? (float)(quad * 8 + i)      : (ln16 == 1 ? 1.f : 0.f);
      float c1 = (ln16 == 0) ? (float)(32 + quad * 8 + i) : (ln16 == 1 ? 1.f : 0.f);
      cf0[i] = (_Float16)c0;
      cf1[i] = (_Float16)c1;
    }
  }

  floatx4 accO[8];
  #pragma unroll
  for (int v = 0; v < 8; v++) accO[v] = (floatx4)0.0f;
  floatx4 accE  = (floatx4)0.0f;   // even-j: [0]=Σp·kk, [1]=Σp (quad0 rows)
  floatx4 accEo = (floatx4)0.0f;   // odd-j
  float m_q = -3.0e38f;

  const int sk  = tid >> 4, scb = tid & 15;  // phi staging
  const int gv_ = tid >> 3, gcb = tid & 7;   // g staging

  uintx4 sp[4], sg[4];
  #pragma unroll
  for (int i = 0; i < 4; i++) {
    sp[i] = *(const uintx4*)(phiT + (size_t)(b * HW + i * 16 + sk) * RP + scb * 8);
    sg[i] = *(const uintx4*)(gT + (size_t)(b * RP + i * 32 + gv_) * HW + gcb * 8);
  }

  #pragma unroll 1
  for (int j = 0; j < 64; j++) {
    #pragma unroll
    for (int i = 0; i < 4; i++) {
      phi_lds[scb * 65 + i * 16 + sk] = sp[i];
      g_lds[gcb * 129 + i * 32 + gv_] = sg[i];
    }
    if (j < 63) {
      const int k0n = (j + 1) * 64;
      #pragma unroll
      for (int i = 0; i < 4; i++) {
        sp[i] = *(const uintx4*)(phiT + (size_t)(b * HW + k0n + i * 16 + sk) * RP + scb * 8);
        sg[i] = *(const uintx4*)(gT + (size_t)(b * RP + i * 32 + gv_) * HW + k0n + gcb * 8);
      }
    }
    barrier_nodrain();

    floatx4 sf[4];
    #pragma unroll
    for (int s = 0; s < 4; s++) sf[s] = (floatx4)0.0f;
    __builtin_amdgcn_s_setprio(1);
    #pragma unroll
    for (int c = 0; c < 4; c++) {
      half8 bth = as_h8(aq[c]);
      #pragma unroll
      for (int s = 0; s < 4; s++) {
        uintx4 ap = phi_lds[(c * 4 + quad) * 65 + s * 16 + ln16];
        sf[s] = __builtin_amdgcn_mfma_f32_16x16x32_f16(as_h8(ap), bth, sf[s], 0, 0, 0);
      }
    }
    __builtin_amdgcn_s_setprio(0);

    float ms0 = fmaxf(fmaxf(sf[0][0], sf[0][1]), fmaxf(sf[0][2], sf[0][3]));
    float ms1 = fmaxf(fmaxf(sf[1][0], sf[1][1]), fmaxf(sf[1][2], sf[1][3]));
    float ms2 = fmaxf(fmaxf(sf[2][0], sf[2][1]), fmaxf(sf[2][2], sf[2][3]));
    float ms3 = fmaxf(fmaxf(sf[3][0], sf[3][1]), fmaxf(sf[3][2], sf[3][3]));
    float mx = fmaxf(fmaxf(ms0, ms1), fmaxf(ms2, ms3));
    mx = fmaxf(mx, __shfl_xor(mx, 16));
    mx = fmaxf(mx, __shfl_xor(mx, 32));
    if (__any(mx > m_q + 8.f)) {       // wave-uniform, rare in steady state
      const float mnew  = fmaxf(m_q, mx);
      const float alpha = __expf(m_q - mnew);
      m_q = mnew;
      accE *= alpha; accEo *= alpha;
      #pragma unroll
      for (int v = 0; v < 8; v++) accO[v] *= alpha;
    }
    // P in registers: lane (ln16,quad) holds keys 16s+4*quad+r.
    float pv[4][4];
    #pragma unroll
    for (int s = 0; s < 4; s++) {
      pv[s][0] = __expf(sf[s][0] - m_q);
      pv[s][1] = __expf(sf[s][1] - m_q);
      pv[s][2] = __expf(sf[s][2] - m_q);
      pv[s][3] = __expf(sf[s][3] - m_q);
    }
    // Route to PV B-fragment layout (lane quad needs keys 8*quad + i).
    u32 x0 = pkrtz(pv[0][0], pv[0][1]), z0 = pkrtz(pv[1][0], pv[1][1]);
    route_p(x0, z0);
    u32 y0 = pkrtz(pv[0][2], pv[0][3]), w0 = pkrtz(pv[1][2], pv[1][3]);
    route_p(y0, w0);
    u32 x1 = pkrtz(pv[2][0], pv[2][1]), z1 = pkrtz(pv[3][0], pv[3][1]);
    route_p(x1, z1);
    u32 y1 = pkrtz(pv[2][2], pv[2][3]), w1 = pkrtz(pv[3][2], pv[3][3]);
    route_p(y1, w1);
    uintx4 pb0v; pb0v[0] = x0; pb0v[1] = y0; pb0v[2] = z0; pb0v[3] = w0;
    uintx4 pb1v; pb1v[0] = x1; pb1v[1] = y1; pb1v[2] = z1; pb1v[3] = w1;
    half8 pb0 = as_h8(pb0v);
    half8 pb1 = as_h8(pb1v);

    __builtin_amdgcn_s_setprio(1);
    #pragma unroll
    for (int vt = 0; vt < 8; vt++) {
      uintx4 ag0 = g_lds[quad * 129 + vt * 16 + ln16];
      uintx4 ag1 = g_lds[(4 + quad) * 129 + vt * 16 + ln16];
      accO[vt] = __builtin_amdgcn_mfma_f32_16x16x32_f16(as_h8(ag0), pb0, accO[vt], 0, 0, 0);
      accO[vt] = __builtin_amdgcn_mfma_f32_16x16x32_f16(as_h8(ag1), pb1, accO[vt], 0, 0, 0);
    }
    if (j & 1) {
      accEo = __builtin_amdgcn_mfma_f32_16x16x32_f16(cf0, pb0, accEo, 0, 0, 0);
      accEo = __builtin_amdgcn_mfma_f32_16x16x32_f16(cf1, pb1, accEo, 0, 0, 0);
    } else {
      accE  = __builtin_amdgcn_mfma_f32_16x16x32_f16(cf0, pb0, accE, 0, 0, 0);
      accE  = __builtin_amdgcn_mfma_f32_16x16x32_f16(cf1, pb1, accE, 0, 0, 0);
    }
    __builtin_amdgcn_s_setprio(0);
    barrier_nodrain();
  }

  // epilogue: l = Σp (all j), aC = Σp·kk + 64·Σp(odd j); broadcast via shfl.
  const float l0 = accE[1] + accEo[1];
  const float a0 = accE[0] + accEo[0] + 64.f * accEo[1];
  const float l_all  = __shfl(l0, ln16);
  const float aC_all = __shfl(a0, ln16);

  const int q = q0 + wv * 16 + ln16;
  const size_t p = (size_t)b * HW + q;
  u16* after = side ? afterR : afterL;
  u16* orow = after + p * RP;
  const float invl = 1.f / l_all;
  #pragma unroll
  for (int vt = 0; vt < 8; vt++) {
    uintx2 pkv;
    pkv[0] = pkrtz(accO[vt][0] * invl, accO[vt][1] * invl);
    pkv[1] = pkrtz(accO[vt][2] * invl, accO[vt][3] * invl);
    *(uintx2*)(orow + vt * 16 + quad * 4) = pkv;
  }
  if (quad == 0) {
    float* idx = side ? idxR : idxL;
    idx[p] = (float)(q & 127) - aC_all * invl;
  }
}

// ---------------------------------------------------------------------------
// Up-projection stats only (R17): MFMA y, Σy/Σy² atomics, XCD swizzle.
// ---------------------------------------------------------------------------
#define WSTR 136   // u16 stride (272B, 16B-aligned rows)

__global__ __launch_bounds__(256) void ra_upstats(
    const u16* __restrict__ afterL, const u16* __restrict__ afterR,
    const float* __restrict__ w, const float* __restrict__ bias,
    float* __restrict__ stL, float* __restrict__ stR)
{
  __shared__ u16 w_lds[128 * WSTR];   // [co][r]; reused as float scratch
  const int tid  = threadIdx.x;
  const int h    = blockIdx.x;
  const int bx   = ((h & 7) << 6) | (h >> 3);   // XCD-group swizzle (512 = 8x64)
  const int side = bx >> 8;
  const int sbx  = bx & 255;
  const u16* __restrict__ after = side ? afterR : afterL;
  const int b    = sbx >> 6;
  const int pos0 = ((sbx >> 1) & 31) * 128;
  const int hc   = sbx & 1;
  const int wv   = tid >> 6;
  const int lane = tid & 63;
  const int ln16 = lane & 15;
  const int quad = lane >> 4;

  {
    const int co = tid >> 1, rh = (tid & 1) * 64;
    const float* wp = w + (size_t)(hc * 128 + co) * RP + rh;
    #pragma unroll
    for (int i = 0; i < 8; i++) {
      floatx4 f0 = *(const floatx4*)(wp + i * 8);
      floatx4 f1 = *(const floatx4*)(wp + i * 8 + 4);
      uintx4 v;
      v[0] = pk2h(f0[0], f0[1]); v[1] = pk2h(f0[2], f0[3]);
      v[2] = pk2h(f1[0], f1[1]); v[3] = pk2h(f1[2], f1[3]);
      *(uintx4*)&w_lds[co * WSTR + rh + i * 8] = v;
    }
  }
  __syncthreads();

  floatx4 acc[2][8];
  #pragma unroll
  for (int mt = 0; mt < 2; mt++)
    #pragma unroll
    for (int nt = 0; nt < 8; nt++) acc[mt][nt] = (floatx4)0.0f;

  #pragma unroll
  for (int kk = 0; kk < 4; kk++) {
    half8 a[2];
    #pragma unroll
    for (int mt = 0; mt < 2; mt++)
      a[mt] = as_h8(*(const uintx4*)(after +
          (size_t)(b * HW + pos0 + wv * 32 + mt * 16 + ln16) * RP + kk * 32 + quad * 8));
    #pragma unroll
    for (int nt = 0; nt < 8; nt++) {
      half8 bf = as_h8(*(const uintx4*)&w_lds[(nt * 16 + ln16) * WSTR + kk * 32 + quad * 8]);
      acc[0][nt] = __builtin_amdgcn_mfma_f32_16x16x32_f16(a[0], bf, acc[0][nt], 0, 0, 0);
      acc[1][nt] = __builtin_amdgcn_mfma_f32_16x16x32_f16(a[1], bf, acc[1][nt], 0, 0, 0);
    }
  }

  // per-channel partials (this block: 128 pos of one b)
  float s_nt[8], q_nt[8];
  #pragma unroll
  for (int nt = 0; nt < 8; nt++) {
    const float bs = bias[hc * 128 + nt * 16 + ln16];
    float s = 0.f, sq = 0.f;
    #pragma unroll
    for (int mt = 0; mt < 2; mt++) {
      #pragma unroll
      for (int rr = 0; rr < 4; rr++) {
        const float yv = acc[mt][nt][rr] + bs;
        s += yv; sq += yv * yv;
      }
    }
    s  += __shfl_xor(s, 16);  s  += __shfl_xor(s, 32);
    sq += __shfl_xor(sq, 16); sq += __shfl_xor(sq, 32);
    s_nt[nt] = s; q_nt[nt] = sq;
  }
  __syncthreads();              // all waves done reading w_lds
  float* scr = (float*)w_lds;   // [0..511]=s per (wv,co), [512..1023]=sq
  if (quad == 0) {
    #pragma unroll
    for (int nt = 0; nt < 8; nt++) {
      scr[wv * 128 + nt * 16 + ln16]       = s_nt[nt];
      scr[512 + wv * 128 + nt * 16 + ln16] = q_nt[nt];
    }
  }
  __syncthreads();
  if (tid < 128) {
    const float s  = scr[tid] + scr[128 + tid] + scr[256 + tid] + scr[384 + tid];
    const float sq = scr[512 + tid] + scr[640 + tid] + scr[768 + tid] + scr[896 + tid];
    float* stats = side ? stR : stL;
    atomicAdd(&stats[2 * (hc * 128 + tid)], s);
    atomicAdd(&stats[2 * (hc * 128 + tid) + 1], sq);
  }
}

// ---------------------------------------------------------------------------
// Fused up-projection + batch-norm + residual (R17): XCD swizzle.
// ---------------------------------------------------------------------------
__global__ __launch_bounds__(256) void ra_finm(
    const u16* __restrict__ afterL, const u16* __restrict__ afterR,
    const float* __restrict__ w, const float* __restrict__ bias,
    const float* __restrict__ left, const float* __restrict__ right,
    const float* __restrict__ stL, const float* __restrict__ stR,
    const float* __restrict__ gamma, const float* __restrict__ beta,
    float* __restrict__ out)
{
  __shared__ u16 w_lds[128 * WSTR];   // [co][r]
  const int tid  = threadIdx.x;
  const int h    = blockIdx.x;
  const int bx   = ((h & 7) << 6) | (h >> 3);   // XCD-group swizzle (512 = 8x64)
  const int side = bx >> 8;
  const int sbx  = bx & 255;
  const u16* __restrict__ after = side ? afterR : afterL;
  const int b    = sbx >> 6;
  const int pos0 = ((sbx >> 1) & 31) * 128;
  const int hc   = sbx & 1;
  const int wv   = tid >> 6;
  const int lane = tid & 63;
  const int ln16 = lane & 15;
  const int quad = lane >> 4;

  {
    const int co = tid >> 1, rh = (tid & 1) * 64;
    const float* wp = w + (size_t)(hc * 128 + co) * RP + rh;
    #pragma unroll
    for (int i = 0; i < 8; i++) {
      floatx4 f0 = *(const floatx4*)(wp + i * 8);
      floatx4 f1 = *(const floatx4*)(wp + i * 8 + 4);
      uintx4 v;
      v[0] = pk2h(f0[0], f0[1]); v[1] = pk2h(f0[2], f0[3]);
      v[2] = pk2h(f1[0], f1[1]); v[3] = pk2h(f1[2], f1[3]);
      *(uintx4*)&w_lds[co * WSTR + rh + i * 8] = v;
    }
  }
  __syncthreads();

  floatx4 acc[2][8];
  #pragma unroll
  for (int mt = 0; mt < 2; mt++)
    #pragma unroll
    for (int nt = 0; nt < 8; nt++) acc[mt][nt] = (floatx4)0.0f;

  #pragma unroll
  for (int kk = 0; kk < 4; kk++) {
    half8 a[2];
    #pragma unroll
    for (int mt = 0; mt < 2; mt++)
      a[mt] = as_h8(*(const uintx4*)(after +
          (size_t)(b * HW + pos0 + wv * 32 + mt * 16 + ln16) * RP + kk * 32 + quad * 8));
    #pragma unroll
    for (int nt = 0; nt < 8; nt++) {
      half8 bf = as_h8(*(const uintx4*)&w_lds[(nt * 16 + ln16) * WSTR + kk * 32 + quad * 8]);
      acc[0][nt] = __builtin_amdgcn_mfma_f32_16x16x32_f16(a[0], bf, acc[0][nt], 0, 0, 0);
      acc[1][nt] = __builtin_amdgcn_mfma_f32_16x16x32_f16(a[1], bf, acc[1][nt], 0, 0, 0);
    }
  }

  const float* x = side ? right : left;
  const float* stats = side ? stR : stL;
  float* outs = out + (size_t)side * 4194304;
  #pragma unroll
  for (int nt = 0; nt < 8; nt++) {
    const int co = hc * 128 + nt * 16 + ln16;
    const float s = stats[2 * co], sq = stats[2 * co + 1];
    const float mean = s * (1.f / 16384.f);
    const float var  = sq * (1.f / 16384.f) - mean * mean;
    const float rstd = rsqrtf(var + EPSF);
    const float ga = gamma[co], be = beta[co];
    const float bs = bias[co];
    #pragma unroll
    for (int mt = 0; mt < 2; mt++) {
      const int pv = pos0 + wv * 32 + mt * 16 + quad * 4;
      floatx4 xv = *(const floatx4*)(x + (size_t)(b * CB + co) * HW + pv);
      floatx4 o;
      #pragma unroll
      for (int rr = 0; rr < 4; rr++) {
        const float yv = acc[mt][nt][rr] + bs;
        o[rr] = xv[rr] + ga * ((yv - mean) * rstd) + be;
      }
      *(floatx4*)(outs + (size_t)(b * CB + co) * HW + pv) = o;
    }
  }
}

// ---------------------------------------------------------------------------
extern "C" void kernel_launch(void* const* d_in, const int* in_sizes, int n_in,
                              void* d_out, int out_size, void* d_ws, size_t ws_size,
                              hipStream_t stream)
{
  const float* left    = (const float*)d_in[0];
  const float* right   = (const float*)d_in[1];
  const float* pre_l   = (const float*)d_in[2];
  const float* pre_r   = (const float*)d_in[3];
  const float* query_l = (const float*)d_in[4];
  const float* key_l   = (const float*)d_in[5];
  const float* query_r = (const float*)d_in[6];
  const float* key_r   = (const float*)d_in[7];
  const float* theta_w = (const float*)d_in[8];
  const float* theta_b = (const float*)d_in[9];
  const float* phi_w   = (const float*)d_in[10];
  const float* phi_b   = (const float*)d_in[11];
  const float* g_w     = (const float*)d_in[12];
  const float* g_b     = (const float*)d_in[13];
  const float* up_w    = (const float*)d_in[14];
  const float* up_b    = (const float*)d_in[15];
  const float* bn_g    = (const float*)d_in[16];
  const float* bn_b    = (const float*)d_in[17];
  float* out = (float*)d_out;

  char* ws = (char*)d_ws;
  const size_t SZ = (size_t)4 * HW * RP * 2;  // 4 MiB (fp16 [4][4096][128])
  u16* thetaL = (u16*)(ws);
  u16* phiTL  = (u16*)(ws + 1 * SZ);
  u16* gTL    = (u16*)(ws + 2 * SZ);
  u16* thetaR = (u16*)(ws + 3 * SZ);
  u16* phiTR  = (u16*)(ws + 4 * SZ);
  u16* gTR    = (u16*)(ws + 5 * SZ);
  u16* afterL = (u16*)(ws + 6 * SZ);
  u16* afterR = (u16*)(ws + 7 * SZ);
  float* stL  = (float*)(ws + 8 * SZ);
  float* stR  = (float*)(ws + 8 * SZ + 2048);

  dim3 blk(256);
  // side L: x_q=left, x_kv=right, query_l, key_r; side R mirrored.
  ProjCfg6 pc;
  pc.c[0] = { left,  theta_w, theta_b, query_l, pre_l,   thetaL, 257, 0 };
  pc.c[1] = { right, phi_w,   phi_b,   key_r,   nullptr, phiTL,  256, 0 };
  pc.c[2] = { right, g_w,     g_b,     nullptr, nullptr, gTL,    256, 1 };
  pc.c[3] = { right, theta_w, theta_b, query_r, pre_r,   thetaR, 257, 0 };
  pc.c[4] = { left,  phi_w,   phi_b,   key_l,   nullptr, phiTR,  256, 0 };
  pc.c[5] = { left,  g_w,     g_b,     nullptr, nullptr, gTR,    256, 1 };
  ra_projm<<<768, blk, 0, stream>>>(pc, stL);

  ra_flash<<<512, blk, 0, stream>>>(thetaL, phiTL, gTL, thetaR, phiTR, gTR,
                                    afterL, afterR,
                                    out + 8388608, out + 8404992);
  ra_upstats<<<512, blk, 0, stream>>>(afterL, afterR, up_w, up_b, stL, stR);
  ra_finm<<<512, blk, 0, stream>>>(afterL, afterR, up_w, up_b, left, right,
                                   stL, stR, bn_g, bn_b, out);

  (void)in_sizes; (void)n_in; (void)out_size; (void)ws_size;
}